// Round 17
// baseline (246.103 us; speedup 1.0000x reference)
//
#include <hip/hip_runtime.h>
#include <hip/hip_bf16.h>
#include <math.h>

#define BATCH 256
#define DMODEL 256
#define NHEAD 8
#define DHEAD 32
#define LP1 257
#define TILE2 66049                  // 257*257
#define CH 9                         // 32-row compute chunks per (b,h)
#define NFILL 2                      // fill blocks per (b,h)
#define SCALE 0.17677669529663687f   // 1/sqrt(32)

// LESSON (R12/R13): do NOT fuse the CLS readout into k_attn (VGPR 164 +
// straggler blocks: k_attn 150 -> 390-455 us). Separate small kernel.
// LESSON (R12 vs R13 pair, confirmed R16): per-wave no-barrier vec4 drain
// beats block-barrier scalar drain (262 -> 239 us).

typedef __attribute__((ext_vector_type(8))) _Float16 half8;
typedef __attribute__((ext_vector_type(4))) _Float16 half4;
typedef __attribute__((ext_vector_type(4))) float floatx4;

// ------------- kernel 1: prep = local scan + pack rows to f16 + Wt ------------
__global__ __launch_bounds__(256) void k_prep(const float* __restrict__ x,
                                              const float* __restrict__ cls_emb,
                                              const float* __restrict__ Wq,
                                              const float* __restrict__ Wk,
                                              const int* __restrict__ lengths,
                                              int M, int packN,
                                              _Float16* __restrict__ Ah,
                                              _Float16* __restrict__ Wt,
                                              int* __restrict__ valid_off_g) {
    __shared__ int vo[BATCH];
    __shared__ int ln[BATCH];
    int bx = blockIdx.x, t = threadIdx.x;

    int v = lengths[t];
    ln[t] = v;
    vo[t] = v;
    __syncthreads();
    for (int d = 1; d < BATCH; d <<= 1) {
        int add = (t >= d) ? vo[t - d] : 0;
        __syncthreads();
        vo[t] += add;
        __syncthreads();
    }
    int ivo = vo[t] - v + t;
    __syncthreads();
    vo[t] = ivo;
    __syncthreads();

    if (bx < packN) {
        int row = bx * 8 + (t >> 5);
        int lane32 = t & 31;
        half8 hv = {};
        if (row < M) {
            int lo = 0, hi = 255;
            #pragma unroll
            for (int it = 0; it < 8; ++it) {
                int mid = (lo + hi + 1) >> 1;
                if (vo[mid] <= row) lo = mid; else hi = mid - 1;
            }
            int p = row - vo[lo];
            const float* src = (p < ln[lo]) ? (x + (size_t)(row - lo) * DMODEL) : cls_emb;
            float4 v0 = *(const float4*)&src[lane32 * 8];
            float4 v1 = *(const float4*)&src[lane32 * 8 + 4];
            hv[0] = (_Float16)v0.x; hv[1] = (_Float16)v0.y; hv[2] = (_Float16)v0.z; hv[3] = (_Float16)v0.w;
            hv[4] = (_Float16)v1.x; hv[5] = (_Float16)v1.y; hv[6] = (_Float16)v1.z; hv[7] = (_Float16)v1.w;
        }
        *(half8*)&Ah[(size_t)row * DMODEL + lane32 * 8] = hv;
    } else {
        if (bx == packN) valid_off_g[t] = vo[t];
        int n = (bx - packN) * 8 + (t >> 5);
        int k0 = (t & 31) * 8;
        const float* W = (n < 256) ? Wq : Wk;
        int nc = n & 255;
        half8 hv;
        #pragma unroll
        for (int j = 0; j < 8; ++j) hv[j] = (_Float16)W[(size_t)(k0 + j) * DMODEL + nc];
        *(half8*)&Wt[(size_t)n * DMODEL + k0] = hv;
    }
}

// ---------------- kernel 2: MFMA f16 GEMM -> head-major Qh|Kh -----------------
__global__ __launch_bounds__(256) void k_gemm(const _Float16* __restrict__ Ah,
                                              const _Float16* __restrict__ Wt,
                                              int rows_pad,
                                              _Float16* __restrict__ Qh,
                                              _Float16* __restrict__ Kh) {
    __shared__ _Float16 As[128][72];
    __shared__ _Float16 Bs[128][72];
    int t = threadIdx.x;
    int l = t & 63, w = t >> 6;
    int wm = (w >> 1) * 64, wn = (w & 1) * 64;
    int r0 = blockIdx.x * 128;
    int col0 = blockIdx.y * 128;
    int li = l & 15, k0 = (l >> 4) * 8;

    floatx4 acc[4][4] = {};

    for (int kc = 0; kc < 256; kc += 64) {
        #pragma unroll
        for (int jj = 0; jj < 4; ++jj) {
            int idx = t + jj * 256;
            int rl = idx >> 3, q = idx & 7;
            *(half8*)&As[rl][q * 8] = *(const half8*)&Ah[(size_t)(r0 + rl) * DMODEL + kc + q * 8];
            *(half8*)&Bs[rl][q * 8] = *(const half8*)&Wt[(size_t)(col0 + rl) * DMODEL + kc + q * 8];
        }
        __syncthreads();
        half8 a[4][2], bf[4][2];
        #pragma unroll
        for (int m = 0; m < 4; ++m) {
            a[m][0] = *(half8*)&As[wm + m * 16 + li][k0];
            a[m][1] = *(half8*)&As[wm + m * 16 + li][k0 + 32];
        }
        #pragma unroll
        for (int n = 0; n < 4; ++n) {
            bf[n][0] = *(half8*)&Bs[wn + n * 16 + li][k0];
            bf[n][1] = *(half8*)&Bs[wn + n * 16 + li][k0 + 32];
        }
        #pragma unroll
        for (int s = 0; s < 2; ++s)
            #pragma unroll
            for (int m = 0; m < 4; ++m)
                #pragma unroll
                for (int n = 0; n < 4; ++n)
                    acc[m][n] = __builtin_amdgcn_mfma_f32_16x16x32_f16(a[m][s], bf[n][s], acc[m][n], 0, 0, 0);
        __syncthreads();
    }

    int rfrag = (l >> 4) * 4;
    #pragma unroll
    for (int n = 0; n < 4; ++n) {
        int cg = col0 + wn + n * 16 + li;
        _Float16* dst = (cg < 256) ? Qh : Kh;
        size_t hb = (size_t)((cg >> 5) & 7) * rows_pad;
        int cc = cg & 31;
        #pragma unroll
        for (int m = 0; m < 4; ++m) {
            int row = r0 + wm + m * 16 + rfrag;
            #pragma unroll
            for (int f = 0; f < 4; ++f)
                dst[(hb + row + f) * DHEAD + cc] = (_Float16)acc[m][n][f];
        }
    }
}

// ------ kernel 3: MFMA attention, 128-thread blocks, per-wave drain -----------
// 2 waves/block, 32-row chunks (CH=9): finer granules pack the scheduler tail.
// Per-wave compute/stage/drain identical to R16 (proven).
#define WSLICE 4116   // halfs per wave slice (16*257+4, 8B-multiple)
__global__ __launch_bounds__(128) void k_attn(const _Float16* __restrict__ Qh,
                                              const _Float16* __restrict__ Kh,
                                              const int* __restrict__ lengths,
                                              const int* __restrict__ valid_off,
                                              int rows_pad,
                                              float* __restrict__ alpha) {
    int c = blockIdx.x, b = blockIdx.y, h = blockIdx.z;
    int len  = __builtin_amdgcn_readfirstlane(lengths[b]);
    int base = __builtin_amdgcn_readfirstlane(valid_off[b]);
    int t = threadIdx.x;
    float* out = alpha + (size_t)(b * NHEAD + h) * (size_t)TILE2;

    if (c >= CH) {
        // ---- fill partition: rows len+1..256 = 1/257, vec4 NT stream ----
        if (len >= 256) return;
        const float inv257 = 1.f / 257.f;
        int S = (len + 1) * LP1;
        int E = TILE2;
        int half = ((E - S) / NFILL) & ~3;
        int fs = S + (c - CH) * half;
        int fe = (c - CH == NFILL - 1) ? E : fs + half;
        int A = (fs + 3) & ~3;
        if (fs + t < A && fs + t < fe) __builtin_nontemporal_store(inv257, &out[fs + t]);
        int B4 = fe & ~3;
        floatx4 v4 = {inv257, inv257, inv257, inv257};
        for (int j = (A >> 2) + t; (j << 2) < B4; j += 128)
            __builtin_nontemporal_store(v4, (floatx4*)&out[j << 2]);
        if (B4 + t < fe) __builtin_nontemporal_store(inv257, &out[B4 + t]);
        return;
    }

    int r0 = c * 32;
    if (r0 > len) return;

    __shared__ __align__(16) _Float16 smem[2 * WSLICE];   // 16.5 KB

    int l = t & 63;
    int w = t >> 6;                  // wave id 0/1
    int rt = r0 + w * 16;            // wave's 16-row tile
    if (rt > len) return;            // wave-uniform, no barriers below

    int li = l & 15, k0 = (l >> 4) * 8;
    bool full = (len == 256);

    const _Float16* Qb = Qh + ((size_t)h * rows_pad + base) * DHEAD;
    const _Float16* Kb = Kh + ((size_t)h * rows_pad + base) * DHEAD;

    half8 a = *(const half8*)&Qb[(rt + li) * DHEAD + k0];

    floatx4 acc[16];
    #pragma unroll
    for (int g = 0; g < 2; ++g) {
        half8 bf[8];
        #pragma unroll
        for (int j = 0; j < 8; ++j)
            bf[j] = *(const half8*)&Kb[((g * 8 + j) * 16 + li) * DHEAD + k0];
        #pragma unroll
        for (int j = 0; j < 8; ++j)
            acc[g * 8 + j] = __builtin_amdgcn_mfma_f32_16x16x32_f16(a, bf[j], (floatx4){0.f, 0.f, 0.f, 0.f}, 0, 0, 0);
    }

    float p256[4] = {0.f, 0.f, 0.f, 0.f};
    if (full) {
        half8 b256 = {};
        if (li == 0) b256 = *(const half8*)&Kb[256 * DHEAD + k0];
        floatx4 a256 = __builtin_amdgcn_mfma_f32_16x16x32_f16(a, b256, (floatx4){0.f, 0.f, 0.f, 0.f}, 0, 0, 0);
        #pragma unroll
        for (int f = 0; f < 4; ++f) p256[f] = __expf(a256[f] * SCALE);
    }

    float rowsum[4] = {0.f, 0.f, 0.f, 0.f};
    #pragma unroll
    for (int ct = 0; ct < 16; ++ct) {
        bool cm = (ct * 16 + li) <= len;
        #pragma unroll
        for (int f = 0; f < 4; ++f) {
            float pv = cm ? __expf(acc[ct][f] * SCALE) : 0.f;
            acc[ct][f] = pv;
            rowsum[f] += pv;
        }
    }
    if (full && li == 0) {
        #pragma unroll
        for (int f = 0; f < 4; ++f) rowsum[f] += p256[f];
    }
    #pragma unroll
    for (int off = 1; off < 16; off <<= 1) {
        #pragma unroll
        for (int f = 0; f < 4; ++f) rowsum[f] += __shfl_xor(rowsum[f], off);
    }

    // stage into this wave's LDS slice, shifted by global misalignment
    size_t ge = (size_t)(b * NHEAD + h) * TILE2 + (size_t)rt * LP1;
    int aoff = (int)(ge & 3);
    _Float16* wt = smem + w * WSLICE;
    #pragma unroll
    for (int f = 0; f < 4; ++f) {
        int row = rt + (l >> 4) * 4 + f;
        if (row <= len) {
            float inv = 1.f / rowsum[f];
            int lb = aoff + (row - rt) * LP1;
            #pragma unroll
            for (int ct = 0; ct < 16; ++ct)
                wt[lb + ct * 16 + li] = (_Float16)(acc[ct][f] * inv);
            if (li == 0)
                wt[lb + 256] = (_Float16)(full ? p256[f] * inv : 0.f);
        }
    }

    // per-wave drain: aligned dwordx4 NT stores (same-wave LDS ordering)
    int nrows = min(len, rt + 15) - rt + 1;
    int cnt = nrows * LP1;
    float* gA = alpha + (ge - aoff);          // 16B-aligned
    int nch = (aoff + cnt + 3) >> 2;
    for (int k = l; k < nch; k += 64) {
        int s = k * 4;
        if (s >= aoff && s + 4 <= aoff + cnt) {
            half4 hv = *(half4*)&wt[s];
            floatx4 v = {(float)hv[0], (float)hv[1], (float)hv[2], (float)hv[3]};
            __builtin_nontemporal_store(v, (floatx4*)&gA[s]);
        } else {
            #pragma unroll
            for (int j = 0; j < 4; ++j) {
                int idx = s + j;
                if (idx >= aoff && idx < aoff + cnt)
                    __builtin_nontemporal_store((float)wt[idx], &gA[idx]);
            }
        }
    }
}

// ------- kernel 4: CLS readout (512 threads; x-rows read from packed Ah) ------
__global__ __launch_bounds__(512) void k_out(const _Float16* __restrict__ Ah,
                                             const float* __restrict__ Wv,
                                             const float* __restrict__ Wo,
                                             const int* __restrict__ lengths,
                                             const int* __restrict__ valid_off,
                                             const float* __restrict__ alpha,
                                             float* __restrict__ cls_out) {
    int b = blockIdx.x, t = threadIdx.x;
    int col = t & 255, grp = t >> 8;     // grp 0/1
    int len = lengths[b], base = valid_off[b];

    __shared__ float aw[LP1][8];
    __shared__ float ctx2[2][NHEAD][DMODEL];
    __shared__ float po[2][DMODEL];
    __shared__ float po2[2][DMODEL];

    int L1 = len + 1;
    for (int i = t; i < L1 * 8; i += 512) {
        int y = i >> 3, h = i & 7;
        aw[y][h] = alpha[((size_t)(b * NHEAD + h) * LP1 + len) * LP1 + y];
    }
    __syncthreads();

    float acc[NHEAD] = {};
    int y0 = grp ? (L1 >> 1) : 0;
    int y1 = grp ? L1 : (L1 >> 1);
    for (int y = y0; y < y1; ++y) {
        float xv = (float)Ah[(size_t)(base + y) * DMODEL + col];
        float4 a0 = *(const float4*)&aw[y][0];
        float4 a1 = *(const float4*)&aw[y][4];
        acc[0] += a0.x * xv; acc[1] += a0.y * xv; acc[2] += a0.z * xv; acc[3] += a0.w * xv;
        acc[4] += a1.x * xv; acc[5] += a1.y * xv; acc[6] += a1.z * xv; acc[7] += a1.w * xv;
    }
    #pragma unroll
    for (int h = 0; h < NHEAD; ++h) ctx2[grp][h][col] = acc[h];
    __syncthreads();

    {
        int n = col, h = n >> 5;
        float s = 0.f;
        for (int c = grp * 128; c < grp * 128 + 128; ++c)
            s += (ctx2[0][h][c] + ctx2[1][h][c]) * Wv[(size_t)c * DMODEL + n];
        po[grp][n] = s;
    }
    __syncthreads();

    {
        int n = col;
        float s = 0.f;
        for (int c = grp * 128; c < grp * 128 + 128; ++c)
            s += (po[0][c] + po[1][c]) * Wo[(size_t)c * DMODEL + n];
        po2[grp][n] = s;
    }
    __syncthreads();

    if (grp == 0)
        cls_out[(size_t)b * DMODEL + col] = po2[0][col] + po2[1][col];
}

extern "C" void kernel_launch(void* const* d_in, const int* in_sizes, int n_in,
                              void* d_out, int out_size, void* d_ws, size_t ws_size,
                              hipStream_t stream) {
    const float* x       = (const float*)d_in[0];
    const int*   lengths = (const int*)d_in[1];
    const float* Wq      = (const float*)d_in[3];
    const float* Wk      = (const float*)d_in[4];
    const float* Wv      = (const float*)d_in[5];
    const float* Wo      = (const float*)d_in[6];
    const float* cls_emb = (const float*)d_in[7];

    int total = in_sizes[0] / DMODEL;
    int M = total + BATCH;
    int rows_pad = ((M + 256 + 127) / 128) * 128;

    float* out     = (float*)d_out;
    float* cls_out = out;                        // [256,256]
    float* alpha   = out + BATCH * DMODEL;       // [256,8,257,257]

    char* wsb = (char*)d_ws;
    int* valid_off = (int*)(wsb + 1024);
    size_t o = 2048;
    _Float16* Ah = (_Float16*)(wsb + o);  o += (size_t)rows_pad * DMODEL * 2;
    o = ((o + 255) / 256) * 256;
    _Float16* Wt = (_Float16*)(wsb + o);  o += (size_t)512 * DMODEL * 2;
    o = ((o + 255) / 256) * 256;
    _Float16* Qh = (_Float16*)(wsb + o);  o += (size_t)rows_pad * DMODEL * 2;
    _Float16* Kh = (_Float16*)(wsb + o);

    int packN = rows_pad / 8;

    k_prep<<<packN + 64, 256, 0, stream>>>(x, cls_emb, Wq, Wk, lengths,
                                           M, packN, Ah, Wt, valid_off);

    dim3 g2(rows_pad / 128, 4);
    k_gemm<<<g2, 256, 0, stream>>>(Ah, Wt, rows_pad, Qh, Kh);

    dim3 g3(CH + NFILL, BATCH, NHEAD);
    k_attn<<<g3, 128, 0, stream>>>(Qh, Kh, lengths, valid_off, rows_pad, alpha);

    k_out<<<BATCH, 512, 0, stream>>>(Ah, Wv, Wo, lengths, valid_off, alpha, cls_out);
}

// Round 18
// 238.486 us; speedup vs baseline: 1.0319x; 1.0319x over previous
//
#include <hip/hip_runtime.h>
#include <hip/hip_bf16.h>
#include <math.h>

#define BATCH 256
#define DMODEL 256
#define NHEAD 8
#define DHEAD 32
#define LP1 257
#define TILE2 66049                  // 257*257
#define CH 5                         // 64-row compute chunks per (b,h)
#define NFILL 2                      // fill blocks per (b,h)
#define SCALE 0.17677669529663687f   // 1/sqrt(32)

// LESSON (R12/R13): do NOT fuse the CLS readout into k_attn (VGPR 164 +
// straggler blocks: k_attn 150 -> 390-455 us). Separate small kernel.
// LESSON (R12 vs R13 pair, confirmed R16): per-wave no-barrier vec4 drain
// beats block-barrier scalar drain (262 -> 239 us).
// LESSON (R17): finer blocks (128 thr, 32-row chunks, CH=9) REGRESS (+7 us):
// more per-block overhead than tail-packing gain. CH=5 / 256 thr is tuned.

typedef __attribute__((ext_vector_type(8))) _Float16 half8;
typedef __attribute__((ext_vector_type(4))) _Float16 half4;
typedef __attribute__((ext_vector_type(4))) float floatx4;

// ------------- kernel 1: prep = local scan + pack rows to f16 + Wt ------------
__global__ __launch_bounds__(256) void k_prep(const float* __restrict__ x,
                                              const float* __restrict__ cls_emb,
                                              const float* __restrict__ Wq,
                                              const float* __restrict__ Wk,
                                              const int* __restrict__ lengths,
                                              int M, int packN,
                                              _Float16* __restrict__ Ah,
                                              _Float16* __restrict__ Wt,
                                              int* __restrict__ valid_off_g) {
    __shared__ int vo[BATCH];
    __shared__ int ln[BATCH];
    int bx = blockIdx.x, t = threadIdx.x;

    int v = lengths[t];
    ln[t] = v;
    vo[t] = v;
    __syncthreads();
    for (int d = 1; d < BATCH; d <<= 1) {
        int add = (t >= d) ? vo[t - d] : 0;
        __syncthreads();
        vo[t] += add;
        __syncthreads();
    }
    int ivo = vo[t] - v + t;
    __syncthreads();
    vo[t] = ivo;
    __syncthreads();

    if (bx < packN) {
        int row = bx * 8 + (t >> 5);
        int lane32 = t & 31;
        half8 hv = {};
        if (row < M) {
            int lo = 0, hi = 255;
            #pragma unroll
            for (int it = 0; it < 8; ++it) {
                int mid = (lo + hi + 1) >> 1;
                if (vo[mid] <= row) lo = mid; else hi = mid - 1;
            }
            int p = row - vo[lo];
            const float* src = (p < ln[lo]) ? (x + (size_t)(row - lo) * DMODEL) : cls_emb;
            float4 v0 = *(const float4*)&src[lane32 * 8];
            float4 v1 = *(const float4*)&src[lane32 * 8 + 4];
            hv[0] = (_Float16)v0.x; hv[1] = (_Float16)v0.y; hv[2] = (_Float16)v0.z; hv[3] = (_Float16)v0.w;
            hv[4] = (_Float16)v1.x; hv[5] = (_Float16)v1.y; hv[6] = (_Float16)v1.z; hv[7] = (_Float16)v1.w;
        }
        *(half8*)&Ah[(size_t)row * DMODEL + lane32 * 8] = hv;
    } else {
        if (bx == packN) valid_off_g[t] = vo[t];
        int n = (bx - packN) * 8 + (t >> 5);
        int k0 = (t & 31) * 8;
        const float* W = (n < 256) ? Wq : Wk;
        int nc = n & 255;
        half8 hv;
        #pragma unroll
        for (int j = 0; j < 8; ++j) hv[j] = (_Float16)W[(size_t)(k0 + j) * DMODEL + nc];
        *(half8*)&Wt[(size_t)n * DMODEL + k0] = hv;
    }
}

// ---------------- kernel 2: MFMA f16 GEMM -> head-major Qh|Kh -----------------
__global__ __launch_bounds__(256) void k_gemm(const _Float16* __restrict__ Ah,
                                              const _Float16* __restrict__ Wt,
                                              int rows_pad,
                                              _Float16* __restrict__ Qh,
                                              _Float16* __restrict__ Kh) {
    __shared__ _Float16 As[128][72];
    __shared__ _Float16 Bs[128][72];
    int t = threadIdx.x;
    int l = t & 63, w = t >> 6;
    int wm = (w >> 1) * 64, wn = (w & 1) * 64;
    int r0 = blockIdx.x * 128;
    int col0 = blockIdx.y * 128;
    int li = l & 15, k0 = (l >> 4) * 8;

    floatx4 acc[4][4] = {};

    for (int kc = 0; kc < 256; kc += 64) {
        #pragma unroll
        for (int jj = 0; jj < 4; ++jj) {
            int idx = t + jj * 256;
            int rl = idx >> 3, q = idx & 7;
            *(half8*)&As[rl][q * 8] = *(const half8*)&Ah[(size_t)(r0 + rl) * DMODEL + kc + q * 8];
            *(half8*)&Bs[rl][q * 8] = *(const half8*)&Wt[(size_t)(col0 + rl) * DMODEL + kc + q * 8];
        }
        __syncthreads();
        half8 a[4][2], bf[4][2];
        #pragma unroll
        for (int m = 0; m < 4; ++m) {
            a[m][0] = *(half8*)&As[wm + m * 16 + li][k0];
            a[m][1] = *(half8*)&As[wm + m * 16 + li][k0 + 32];
        }
        #pragma unroll
        for (int n = 0; n < 4; ++n) {
            bf[n][0] = *(half8*)&Bs[wn + n * 16 + li][k0];
            bf[n][1] = *(half8*)&Bs[wn + n * 16 + li][k0 + 32];
        }
        #pragma unroll
        for (int s = 0; s < 2; ++s)
            #pragma unroll
            for (int m = 0; m < 4; ++m)
                #pragma unroll
                for (int n = 0; n < 4; ++n)
                    acc[m][n] = __builtin_amdgcn_mfma_f32_16x16x32_f16(a[m][s], bf[n][s], acc[m][n], 0, 0, 0);
        __syncthreads();
    }

    int rfrag = (l >> 4) * 4;
    #pragma unroll
    for (int n = 0; n < 4; ++n) {
        int cg = col0 + wn + n * 16 + li;
        _Float16* dst = (cg < 256) ? Qh : Kh;
        size_t hb = (size_t)((cg >> 5) & 7) * rows_pad;
        int cc = cg & 31;
        #pragma unroll
        for (int m = 0; m < 4; ++m) {
            int row = r0 + wm + m * 16 + rfrag;
            #pragma unroll
            for (int f = 0; f < 4; ++f)
                dst[(hb + row + f) * DHEAD + cc] = (_Float16)acc[m][n][f];
        }
    }
}

// ------ kernel 3: MFMA attention, per-wave LDS slice + no-barrier drain -------
#define WSLICE 4116   // halfs per wave slice (16*257+4, 8B-multiple)
__global__ __launch_bounds__(256) void k_attn(const _Float16* __restrict__ Qh,
                                              const _Float16* __restrict__ Kh,
                                              const int* __restrict__ lengths,
                                              const int* __restrict__ valid_off,
                                              int rows_pad,
                                              float* __restrict__ alpha) {
    int c = blockIdx.x, b = blockIdx.y, h = blockIdx.z;
    int len  = __builtin_amdgcn_readfirstlane(lengths[b]);
    int base = __builtin_amdgcn_readfirstlane(valid_off[b]);
    int t = threadIdx.x;
    float* out = alpha + (size_t)(b * NHEAD + h) * (size_t)TILE2;

    if (c >= CH) {
        // ---- fill partition: rows len+1..256 = 1/257, vec4 NT stream ----
        if (len >= 256) return;
        const float inv257 = 1.f / 257.f;
        int S = (len + 1) * LP1;
        int E = TILE2;
        int half = ((E - S) / NFILL) & ~3;
        int fs = S + (c - CH) * half;
        int fe = (c - CH == NFILL - 1) ? E : fs + half;
        int A = (fs + 3) & ~3;
        if (fs + t < A && fs + t < fe) __builtin_nontemporal_store(inv257, &out[fs + t]);
        int B4 = fe & ~3;
        floatx4 v4 = {inv257, inv257, inv257, inv257};
        for (int j = (A >> 2) + t; (j << 2) < B4; j += 256)
            __builtin_nontemporal_store(v4, (floatx4*)&out[j << 2]);
        if (B4 + t < fe) __builtin_nontemporal_store(inv257, &out[B4 + t]);
        return;
    }

    int r0 = c * 64;
    if (r0 > len) return;

    __shared__ __align__(16) _Float16 smem[4 * WSLICE];   // 32.9 KB

    int l = t & 63;
    int w = t >> 6;
    int rt = r0 + w * 16;            // wave's 16-row tile
    if (rt > len) return;            // wave-uniform, no barriers below

    int li = l & 15, k0 = (l >> 4) * 8;
    bool full = (len == 256);

    const _Float16* Qb = Qh + ((size_t)h * rows_pad + base) * DHEAD;
    const _Float16* Kb = Kh + ((size_t)h * rows_pad + base) * DHEAD;

    half8 a = *(const half8*)&Qb[(rt + li) * DHEAD + k0];

    floatx4 acc[16];
    #pragma unroll
    for (int g = 0; g < 2; ++g) {
        half8 bf[8];
        #pragma unroll
        for (int j = 0; j < 8; ++j)
            bf[j] = *(const half8*)&Kb[((g * 8 + j) * 16 + li) * DHEAD + k0];
        #pragma unroll
        for (int j = 0; j < 8; ++j)
            acc[g * 8 + j] = __builtin_amdgcn_mfma_f32_16x16x32_f16(a, bf[j], (floatx4){0.f, 0.f, 0.f, 0.f}, 0, 0, 0);
    }

    float p256[4] = {0.f, 0.f, 0.f, 0.f};
    if (full) {
        half8 b256 = {};
        if (li == 0) b256 = *(const half8*)&Kb[256 * DHEAD + k0];
        floatx4 a256 = __builtin_amdgcn_mfma_f32_16x16x32_f16(a, b256, (floatx4){0.f, 0.f, 0.f, 0.f}, 0, 0, 0);
        #pragma unroll
        for (int f = 0; f < 4; ++f) p256[f] = __expf(a256[f] * SCALE);
    }

    float rowsum[4] = {0.f, 0.f, 0.f, 0.f};
    #pragma unroll
    for (int ct = 0; ct < 16; ++ct) {
        bool cm = (ct * 16 + li) <= len;
        #pragma unroll
        for (int f = 0; f < 4; ++f) {
            float pv = cm ? __expf(acc[ct][f] * SCALE) : 0.f;
            acc[ct][f] = pv;
            rowsum[f] += pv;
        }
    }
    if (full && li == 0) {
        #pragma unroll
        for (int f = 0; f < 4; ++f) rowsum[f] += p256[f];
    }
    #pragma unroll
    for (int off = 1; off < 16; off <<= 1) {
        #pragma unroll
        for (int f = 0; f < 4; ++f) rowsum[f] += __shfl_xor(rowsum[f], off);
    }

    // stage into this wave's LDS slice, shifted by global misalignment
    size_t ge = (size_t)(b * NHEAD + h) * TILE2 + (size_t)rt * LP1;
    int aoff = (int)(ge & 3);
    _Float16* wt = smem + w * WSLICE;
    #pragma unroll
    for (int f = 0; f < 4; ++f) {
        int row = rt + (l >> 4) * 4 + f;
        if (row <= len) {
            float inv = 1.f / rowsum[f];
            int lb = aoff + (row - rt) * LP1;
            #pragma unroll
            for (int ct = 0; ct < 16; ++ct)
                wt[lb + ct * 16 + li] = (_Float16)(acc[ct][f] * inv);
            if (li == 0)
                wt[lb + 256] = (_Float16)(full ? p256[f] * inv : 0.f);
        }
    }

    // per-wave drain: aligned dwordx4 NT stores (same-wave LDS ordering)
    int nrows = min(len, rt + 15) - rt + 1;
    int cnt = nrows * LP1;
    float* gA = alpha + (ge - aoff);          // 16B-aligned
    int nch = (aoff + cnt + 3) >> 2;
    for (int k = l; k < nch; k += 64) {
        int s = k * 4;
        if (s >= aoff && s + 4 <= aoff + cnt) {
            half4 hv = *(half4*)&wt[s];
            floatx4 v = {(float)hv[0], (float)hv[1], (float)hv[2], (float)hv[3]};
            __builtin_nontemporal_store(v, (floatx4*)&gA[s]);
        } else {
            #pragma unroll
            for (int j = 0; j < 4; ++j) {
                int idx = s + j;
                if (idx >= aoff && idx < aoff + cnt)
                    __builtin_nontemporal_store((float)wt[idx], &gA[idx]);
            }
        }
    }
}

// ------- kernel 4: CLS readout (512 threads; x-rows read from packed Ah) ------
__global__ __launch_bounds__(512) void k_out(const _Float16* __restrict__ Ah,
                                             const float* __restrict__ Wv,
                                             const float* __restrict__ Wo,
                                             const int* __restrict__ lengths,
                                             const int* __restrict__ valid_off,
                                             const float* __restrict__ alpha,
                                             float* __restrict__ cls_out) {
    int b = blockIdx.x, t = threadIdx.x;
    int col = t & 255, grp = t >> 8;     // grp 0/1
    int len = lengths[b], base = valid_off[b];

    __shared__ float aw[LP1][8];
    __shared__ float ctx2[2][NHEAD][DMODEL];
    __shared__ float po[2][DMODEL];
    __shared__ float po2[2][DMODEL];

    int L1 = len + 1;
    for (int i = t; i < L1 * 8; i += 512) {
        int y = i >> 3, h = i & 7;
        aw[y][h] = alpha[((size_t)(b * NHEAD + h) * LP1 + len) * LP1 + y];
    }
    __syncthreads();

    float acc[NHEAD] = {};
    int y0 = grp ? (L1 >> 1) : 0;
    int y1 = grp ? L1 : (L1 >> 1);
    for (int y = y0; y < y1; ++y) {
        float xv = (float)Ah[(size_t)(base + y) * DMODEL + col];
        float4 a0 = *(const float4*)&aw[y][0];
        float4 a1 = *(const float4*)&aw[y][4];
        acc[0] += a0.x * xv; acc[1] += a0.y * xv; acc[2] += a0.z * xv; acc[3] += a0.w * xv;
        acc[4] += a1.x * xv; acc[5] += a1.y * xv; acc[6] += a1.z * xv; acc[7] += a1.w * xv;
    }
    #pragma unroll
    for (int h = 0; h < NHEAD; ++h) ctx2[grp][h][col] = acc[h];
    __syncthreads();

    {
        int n = col, h = n >> 5;
        float s = 0.f;
        for (int c = grp * 128; c < grp * 128 + 128; ++c)
            s += (ctx2[0][h][c] + ctx2[1][h][c]) * Wv[(size_t)c * DMODEL + n];
        po[grp][n] = s;
    }
    __syncthreads();

    {
        int n = col;
        float s = 0.f;
        for (int c = grp * 128; c < grp * 128 + 128; ++c)
            s += (po[0][c] + po[1][c]) * Wo[(size_t)c * DMODEL + n];
        po2[grp][n] = s;
    }
    __syncthreads();

    if (grp == 0)
        cls_out[(size_t)b * DMODEL + col] = po2[0][col] + po2[1][col];
}

extern "C" void kernel_launch(void* const* d_in, const int* in_sizes, int n_in,
                              void* d_out, int out_size, void* d_ws, size_t ws_size,
                              hipStream_t stream) {
    const float* x       = (const float*)d_in[0];
    const int*   lengths = (const int*)d_in[1];
    const float* Wq      = (const float*)d_in[3];
    const float* Wk      = (const float*)d_in[4];
    const float* Wv      = (const float*)d_in[5];
    const float* Wo      = (const float*)d_in[6];
    const float* cls_emb = (const float*)d_in[7];

    int total = in_sizes[0] / DMODEL;
    int M = total + BATCH;
    int rows_pad = ((M + 256 + 127) / 128) * 128;

    float* out     = (float*)d_out;
    float* cls_out = out;                        // [256,256]
    float* alpha   = out + BATCH * DMODEL;       // [256,8,257,257]

    char* wsb = (char*)d_ws;
    int* valid_off = (int*)(wsb + 1024);
    size_t o = 2048;
    _Float16* Ah = (_Float16*)(wsb + o);  o += (size_t)rows_pad * DMODEL * 2;
    o = ((o + 255) / 256) * 256;
    _Float16* Wt = (_Float16*)(wsb + o);  o += (size_t)512 * DMODEL * 2;
    o = ((o + 255) / 256) * 256;
    _Float16* Qh = (_Float16*)(wsb + o);  o += (size_t)rows_pad * DMODEL * 2;
    _Float16* Kh = (_Float16*)(wsb + o);

    int packN = rows_pad / 8;

    k_prep<<<packN + 64, 256, 0, stream>>>(x, cls_emb, Wq, Wk, lengths,
                                           M, packN, Ah, Wt, valid_off);

    dim3 g2(rows_pad / 128, 4);
    k_gemm<<<g2, 256, 0, stream>>>(Ah, Wt, rows_pad, Qh, Kh);

    dim3 g3(CH + NFILL, BATCH, NHEAD);
    k_attn<<<g3, 256, 0, stream>>>(Qh, Kh, lengths, valid_off, rows_pad, alpha);

    k_out<<<BATCH, 512, 0, stream>>>(Ah, Wv, Wo, lengths, valid_off, alpha, cls_out);
}